// Round 4
// baseline (608.484 us; speedup 1.0000x reference)
//
#include <hip/hip_runtime.h>
#include <stdint.h>

#define B_ 16
#define A_ 9
#define H_ 128
#define W_ 128
#define HW_ (H_*W_)
#define N_ (HW_*A_)          // 147456 proposals per image
#define PRE_ 2000
#define POST_ 300
#define CAND_CAP 4096
#define CACHE_ROWS 576       // supp rows prefetched into LDS in scan (151KB block LDS)

typedef unsigned int u32;
typedef unsigned long long u64;

// ---- workspace layout (bytes) ----
// state + (hist16 overlaid on supp) zeroed by memsetAsync each launch.
#define OFF_STATE  0ull                               // B * 8 u32 = 512 (pad 1024)
#define OFF_KEYS   1024ull
#define OFF_CAND   (OFF_KEYS + (u64)B_*N_*4)
#define OFF_SELBOX (OFF_CAND + (u64)B_*CAND_CAP*8)
#define OFF_LIVE   (OFF_SELBOX + (u64)B_*PRE_*16)
#define OFF_SUPP   (OFF_LIVE + (u64)B_*32*8)          // 16 MB; first 4 MB doubles as hist16
// end = OFF_SUPP + B*PRE*32*8  (~18.7 MB total)

__device__ __forceinline__ u32 mono_key(float f) {
    u32 u = __float_as_uint(f);
    return (u & 0x80000000u) ? ~u : (u | 0x80000000u);
}

__device__ __forceinline__ u64 shfl64(u64 v, int src) {
    u32 lo = (u32)__shfl((int)(u32)(v & 0xFFFFFFFFull), src);
    u32 hi = (u32)__shfl((int)(u32)(v >> 32), src);
    return ((u64)hi << 32) | lo;
}

// ---------------- stage 1: decode + fg scores + keys + 16-bit histogram ----------------
// block = 576 threads (wave a=0..8, lane = p offset); coalesced reads AND writes.
__global__ __launch_bounds__(576) void decode_kernel(
        const float* __restrict__ scores,
        const float* __restrict__ deltas,
        const float* __restrict__ anchors,
        const float* __restrict__ im_info,
        float* __restrict__ outprop,
        u32* __restrict__ keys,
        u32* __restrict__ hist16) {
    __shared__ float4 tile[9][65];   // +1 pad to break write-back bank conflicts
    __shared__ float4 sbase[A_];
    int tid = threadIdx.x;
    int a = tid >> 6, lane = tid & 63;
    if (tid < A_) sbase[tid] = ((const float4*)anchors)[tid];  // anchors[p=0] == base anchors
    __syncthreads();

    int b  = blockIdx.x >> 8;
    int pb = blockIdx.x & 255;
    int p0 = pb << 6;
    int p  = p0 + lane;

    float s0 = scores[((b*2*A_ + a)      << 14) + p];
    float s1 = scores[((b*2*A_ + A_ + a) << 14) + p];
    float m  = fmaxf(s0, s1);
    float e0 = expf(s0 - m);
    float e1 = expf(s1 - m);
    float fg = e1 / (e0 + e1);

    float4 base = sbase[a];
    int ix = p & (W_-1), iy = p >> 7;
    float sx = (float)(ix * 16), sy = (float)(iy * 16);
    float ax1 = base.x + sx, ay1 = base.y + sy, ax2 = base.z + sx, ay2 = base.w + sy;

    float w  = ax2 - ax1 + 1.0f;
    float h_ = ay2 - ay1 + 1.0f;
    float cx = ax1 + 0.5f*w;
    float cy = ay1 + 0.5f*h_;

    const float* dbase = deltas + (u64)(((b*4*A_ + 4*a) << 14) + p);
    float dx = dbase[0];
    float dy = dbase[HW_];
    float dw = dbase[2*HW_];
    float dh = dbase[3*HW_];

    float pcx = dx*w  + cx;
    float pcy = dy*h_ + cy;
    float pw  = expf(dw)*w;
    float ph  = expf(dh)*h_;
    float x1 = pcx - 0.5f*pw, y1 = pcy - 0.5f*ph;
    float x2 = pcx + 0.5f*pw, y2 = pcy + 0.5f*ph;

    float wmax = im_info[b*4 + 1] - 1.0f;
    float hmax = im_info[b*4 + 0] - 1.0f;
    x1 = fminf(fmaxf(x1, 0.0f), wmax);
    y1 = fminf(fmaxf(y1, 0.0f), hmax);
    x2 = fminf(fmaxf(x2, 0.0f), wmax);
    y2 = fminf(fmaxf(y2, 0.0f), hmax);

    tile[a][lane] = make_float4(x1, y1, x2, y2);

    float bw = x2 - x1 + 1.0f;
    float bh = y2 - y1 + 1.0f;
    bool valid = (bw >= 16.0f*im_info[b*4 + 3]) && (bh >= 16.0f*im_info[b*4 + 2]);
    float sc = valid ? fg : -__builtin_inff();
    u32 k = mono_key(sc);
    keys[((u64)(b*A_ + a) << 14) + p] = k;             // coalesced (a,p) layout
    atomicAdd(&hist16[((u64)b << 16) + (k >> 16)], 1u);
    __syncthreads();

    // coalesced write-back: n = p*9 + a; block covers n in [p0*9, p0*9 + 576)
    int j = tid;
    int a2 = j % 9, pl = j / 9;
    ((float4*)outprop)[(u64)b*N_ + p0*9 + j] = tile[a2][pl];
}

// ---------------- stage 2: pick 16-bit threshold bin (1 block / image) ----------------
__global__ __launch_bounds__(1024) void select16_kernel(
        const u32* __restrict__ hist16, u32* __restrict__ state) {
    int b = blockIdx.x, tid = threadIdx.x;
    int wave = tid >> 6, lane = tid & 63;
    const u32* hh = hist16 + ((u64)b << 16);
    u32 local = 0;
    const uint4* hv4 = (const uint4*)(hh + tid*64);
    #pragma unroll
    for (int i = 0; i < 16; ++i) { uint4 v = hv4[i]; local += v.x + v.y + v.z + v.w; }
    // wave-inclusive suffix sum (bins ascend with tid; "above" = larger tid)
    u32 s = local;
    #pragma unroll
    for (int off = 1; off < 64; off <<= 1) {
        u32 o = (u32)__shfl_down((int)s, off);
        if (lane + off < 64) s += o;
    }
    __shared__ u32 wtot[16], wsuf[16];
    if (lane == 0) wtot[wave] = s;
    __syncthreads();
    if (tid < 16) {
        u32 v = wtot[tid], s2 = v;
        #pragma unroll
        for (int off = 1; off < 16; off <<= 1) {
            u32 o = (u32)__shfl_down((int)s2, off);
            if (tid + off < 16) s2 += o;
        }
        wsuf[tid] = s2 - v;           // strictly-above wave total
    }
    __syncthreads();
    u32 above = wsuf[wave] + (s - local);
    if (above < (u32)PRE_ && above + local >= (u32)PRE_) {
        u32 above2 = above;
        for (int i = 63; i >= 0; --i) {
            u32 c = hh[tid*64 + i];
            if (above2 + c >= (u32)PRE_) {
                u32 bin = (u32)(tid*64 + i);
                u32 rem = (u32)PRE_ - above2;
                if (above2 + c <= (u32)CAND_CAP) {
                    state[b*8 + 4] = bin << 16;   // threshold key T
                    state[b*8 + 3] = 1;           // done
                } else {
                    state[b*8 + 0] = bin;         // 16-bit prefix
                    state[b*8 + 1] = rem;
                }
                break;
            }
            above2 += c;
        }
    }
}

// ---------------- stage 2b: rare refine (8-bit then exact), normally early-exits ----------------
__global__ __launch_bounds__(1024) void refine_kernel(
        const u32* __restrict__ keys, u32* __restrict__ state) {
    int b = blockIdx.x, tid = threadIdx.x;
    if (state[b*8 + 3]) return;
    __shared__ u32 h[256];
    __shared__ u32 sP, sRem, sDone;
    if (tid == 0) { sP = state[b*8 + 0]; sRem = state[b*8 + 1]; sDone = 0; }
    const u32* kb = keys + (u64)b*N_;
    for (int lvl = 1; lvl >= 0; --lvl) {
        for (int i = tid; i < 256; i += 1024) h[i] = 0;
        __syncthreads();
        if (!sDone) {
            u32 P = sP;
            if (lvl == 1) { for (int n = tid; n < N_; n += 1024) { u32 k = kb[n]; if ((k >> 16) == P) atomicAdd(&h[(k >> 8) & 255u], 1u); } }
            else          { for (int n = tid; n < N_; n += 1024) { u32 k = kb[n]; if ((k >> 8)  == P) atomicAdd(&h[k & 255u], 1u); } }
        }
        __syncthreads();
        if (!sDone && tid < 64) {
            int lane = tid;
            u32 P = sP, rem0 = sRem;
            uint4 hv = ((const uint4*)h)[lane];
            u32 psum = hv.x + hv.y + hv.z + hv.w;
            u32 s = psum;
            #pragma unroll
            for (int off = 1; off < 64; off <<= 1) {
                u32 o = (u32)__shfl_down((int)s, off);
                if (lane + off < 64) s += o;
            }
            u32 S_next = (u32)__shfl_down((int)s, 1);
            if (lane == 63) S_next = 0;
            u32 above[4], cnt[4];
            above[3] = S_next;             cnt[3] = hv.w;
            above[2] = S_next + hv.w;      cnt[2] = hv.z;
            above[1] = above[2] + hv.z;    cnt[1] = hv.y;
            above[0] = above[1] + hv.y;    cnt[0] = hv.x;
            #pragma unroll
            for (int j = 3; j >= 0; --j) {
                if (above[j] < rem0 && above[j] + cnt[j] >= rem0) {
                    u32 bin = (u32)(4*lane + j);
                    u32 candTotal = ((u32)PRE_ - rem0) + above[j] + cnt[j];
                    if (candTotal <= (u32)CAND_CAP || lvl == 0) {
                        u32 T = (lvl == 1) ? ((P << 16) | (bin << 8)) : ((P << 8) | bin);
                        state[b*8 + 4] = T;
                        state[b*8 + 3] = 1;
                        sDone = 1;
                    } else {
                        sP = (P << 8) | bin;
                        sRem = rem0 - above[j];
                    }
                }
            }
        }
        __syncthreads();
    }
}

// ---------------- stage 3: collect all keys >= T ----------------
__global__ __launch_bounds__(1024) void collect_kernel(
        const u32* __restrict__ keys, u32* __restrict__ state, u64* __restrict__ cand) {
    int b = blockIdx.x >> 4;
    int slice = blockIdx.x & 15;
    u32 T = state[b*8 + 4];
    const u32* kb = keys + (u64)b*N_ + slice*(N_/16);
    u64* cb = cand + (u64)b*CAND_CAP;
    int tid = threadIdx.x;
    for (int i = tid; i < N_/16; i += 1024) {
        u32 k = kb[i];
        if (k >= T) {
            u32 pos = atomicAdd(&state[b*8 + 2], 1u);
            int idx = slice*(N_/16) + i;
            u32 n = (u32)((idx & (HW_-1))*A_ + (idx >> 14));  // n = p*9 + a
            if (pos < CAND_CAP) cb[pos] = ((u64)k << 32) | (u32)(~n);  // key desc, index asc
        }
    }
}

// ---------------- stage 4: bitonic sort candidates, gather top-2000 boxes ----------------
__global__ __launch_bounds__(1024) void sort_kernel(
        const u64* __restrict__ cand, const u32* __restrict__ state,
        const float* __restrict__ outprop,
        float4* __restrict__ selbox, u64* __restrict__ livew) {
    int b = blockIdx.x, tid = threadIdx.x;
    __shared__ u64 s[CAND_CAP];
    __shared__ unsigned char lv[2048];
    u32 cnt = state[b*8 + 2];
    if (cnt > CAND_CAP) cnt = CAND_CAP;
    const u64* cb = cand + (u64)b*CAND_CAP;
    for (int i = tid; i < CAND_CAP; i += 1024) s[i] = (i < (int)cnt) ? cb[i] : 0ull;
    for (int i = tid; i < 2048; i += 1024) lv[i] = 0;

    for (u32 k = 2; k <= CAND_CAP; k <<= 1) {
        for (u32 j = k >> 1; j > 0; j >>= 1) {
            __syncthreads();
            for (u32 e = tid; e < CAND_CAP; e += 1024) {
                u32 ixj = e ^ j;
                if (ixj > e) {
                    u64 x = s[e], y = s[ixj];
                    bool descend = ((e & k) == 0);
                    if (descend ? (x < y) : (x > y)) { s[e] = y; s[ixj] = x; }
                }
            }
        }
    }
    __syncthreads();
    for (int r = tid; r < PRE_; r += 1024) {
        u64 e = s[r];
        u32 key = (u32)(e >> 32);
        u32 n = ~(u32)e;
        float4 box = make_float4(0.f, 0.f, 0.f, 0.f);
        if (e != 0ull) box = ((const float4*)outprop)[(u64)b*N_ + n];
        selbox[(u64)b*PRE_ + r] = box;
        lv[r] = (key >= 0x80000000u) ? 1 : 0;   // finite (valid) score
    }
    __syncthreads();
    for (int w = tid; w < 32; w += 1024) {
        u64 word = 0;
        for (int bit = 0; bit < 64; ++bit) {
            int r = w*64 + bit;
            if (r < PRE_ && lv[r]) word |= (1ull << bit);
        }
        livew[b*32 + w] = word;
    }
}

// ---------------- stage 5: 2000x2000 IoU suppression bitmask (full-device parallel) ----------------
__global__ __launch_bounds__(256) void iou_kernel(
        const float4* __restrict__ selbox, const float* __restrict__ thrp,
        u64* __restrict__ supp) {
    int bi = blockIdx.x;             // B * 250 blocks, 8 rows each
    int b = bi / 250;
    int rbase = (bi % 250) * 8;
    int tid = threadIdx.x;
    __shared__ float4 box[PRE_];
    for (int i = tid; i < PRE_; i += 256) box[i] = selbox[(u64)b*PRE_ + i];
    __syncthreads();
    float thresh = thrp[0];
    int wv = tid >> 6, lane = tid & 63;

    float4 p[8]; float ai[8];
    #pragma unroll
    for (int r = 0; r < 8; ++r) {
        p[r]  = box[rbase + r];
        ai[r] = (p[r].z - p[r].x + 1.f) * (p[r].w - p[r].y + 1.f);
    }
    for (int c = 0; c < 8; ++c) {
        int j = c*256 + tid;
        bool inb = (j < PRE_);
        float4 q = box[inb ? j : 0];
        float aj = (q.z - q.x + 1.f) * (q.w - q.y + 1.f);
        #pragma unroll
        for (int r = 0; r < 8; ++r) {
            float iw = fminf(p[r].z, q.z) - fmaxf(p[r].x, q.x) + 1.f;
            float ih = fminf(p[r].w, q.w) - fmaxf(p[r].y, q.y) + 1.f;
            iw = fmaxf(iw, 0.f); ih = fmaxf(ih, 0.f);
            float inter = iw * ih;
            bool pred = inb && ((inter / (ai[r] + aj - inter)) > thresh);
            u64 ball = __ballot(pred);
            if (lane == 0)
                supp[((u64)(b*PRE_ + rbase + r))*32 + (c*4 + wv)] = ball;
        }
    }
}

// ---------------- stage 6: greedy scan (register state, shfl-only chain) + output ----------------
__global__ __launch_bounds__(1024) void scan_kernel(
        const u64* __restrict__ supp, const u64* __restrict__ livew,
        const float4* __restrict__ selbox, float* __restrict__ out0) {
    int b = blockIdx.x;
    int tid = threadIdx.x;
    int wave = tid >> 6, lane = tid & 63;

    __shared__ u64 rows[CACHE_ROWS][32];     // 147456 B
    __shared__ int rowof[CACHE_ROWS];
    __shared__ int kept[POST_];
    __shared__ int s_kc, s_nlive;

    // wave 0: live words, per-lane exclusive prefix, rowof enumeration
    u64 ow = 0; int pr = 0;
    if (wave == 0) {
        u64 w = (lane < 32) ? livew[b*32 + lane] : 0ull;
        ow = w;
        int pc = (int)__builtin_popcountll(w);
        int x = pc;
        #pragma unroll
        for (int off = 1; off < 64; off <<= 1) {
            int y = __shfl_up(x, off);
            if (lane >= off) x += y;
        }
        pr = x - pc;
        if (lane == 31) s_nlive = x;
        int c = 0;
        u64 t = w;
        while (t) {
            int bit = (int)__builtin_ctzll(t);
            t &= t - 1;
            int slot = pr + c; c++;
            if (slot < CACHE_ROWS) rowof[slot] = lane*64 + bit;
        }
    }
    if (tid == 0) s_kc = 0;
    __syncthreads();

    int nslot = s_nlive < CACHE_ROWS ? s_nlive : CACHE_ROWS;
    for (int s = wave; s < nslot; s += 16) {
        int r = rowof[s];
        if (lane < 32) rows[s][lane] = supp[((u64)(b*PRE_ + r))*32 + lane];
    }
    __syncthreads();

    if (wave == 0) {
        u64 alive = ow;
        u64 gt = ~0ull;
        int kc = 0;
        while (kc < POST_) {
            u64 m = alive & gt;
            u64 bal = __ballot(m != 0ull);
            if (!bal) break;
            int w2 = (int)__builtin_ctzll(bal);
            u64 word = shfl64(m, w2);
            int nxt = (w2 << 6) | (int)__builtin_ctzll(word);
            if (lane == 0) kept[kc] = nxt;
            kc++;
            int nbit = nxt & 63;
            u64 below = (nbit == 0) ? 0ull : (~0ull >> (64 - nbit));
            u64 ow2 = shfl64(ow, w2);
            int pr2 = __shfl(pr, w2);
            int rk = pr2 + (int)__builtin_popcountll(ow2 & below);
            u64 gt2;
            if (lane > w2)       gt2 = ~0ull;
            else if (lane == w2) gt2 = (nbit == 63) ? 0ull : (~0ull << (nbit + 1));
            else                 gt2 = 0ull;
            u64 rv = 0ull;
            if (lane < 32)
                rv = (rk < nslot) ? rows[rk][lane]
                                  : supp[((u64)(b*PRE_ + nxt))*32 + lane];
            alive &= ~(rv & gt2);
            gt = gt2;
        }
        if (lane == 0) s_kc = kc;
    }
    __syncthreads();

    int kc = s_kc;
    for (int r = tid; r < POST_; r += 1024) {
        int i = (r < kc) ? kept[r] : -1;
        float o1 = 0.f, o2 = 0.f, o3 = 0.f, o4 = 0.f;
        if (i >= 0) {
            float4 bx = selbox[(u64)b*PRE_ + i];
            o1 = bx.x; o2 = bx.y; o3 = bx.z; o4 = bx.w;
        }
        float* rowp = out0 + (u64)(b*POST_ + r)*5;
        rowp[0] = (float)b;
        rowp[1] = o1; rowp[2] = o2; rowp[3] = o3; rowp[4] = o4;
    }
}

extern "C" void kernel_launch(void* const* d_in, const int* in_sizes, int n_in,
                              void* d_out, int out_size, void* d_ws, size_t ws_size,
                              hipStream_t stream) {
    const float* scores  = (const float*)d_in[0];
    const float* deltas  = (const float*)d_in[1];
    const float* anchors = (const float*)d_in[2];
    const float* im_info = (const float*)d_in[3];
    const float* thrp    = (const float*)d_in[7];   // nms_thresh

    float* out0    = (float*)d_out;                 // (16, 300, 5)
    float* outprop = out0 + (u64)B_*POST_*5;        // (16, 147456, 4)

    char* ws = (char*)d_ws;
    u32*    state  = (u32*)   (ws + OFF_STATE);
    u32*    keys   = (u32*)   (ws + OFF_KEYS);
    u64*    cand   = (u64*)   (ws + OFF_CAND);
    float4* selbox = (float4*)(ws + OFF_SELBOX);
    u64*    livew  = (u64*)   (ws + OFF_LIVE);
    u64*    supp   = (u64*)   (ws + OFF_SUPP);
    u32*    hist16 = (u32*)   (ws + OFF_SUPP);      // overlay: hist16 used before supp is written

    hipMemsetAsync(state, 0, 1024, stream);
    hipMemsetAsync(hist16, 0, (u64)B_*65536*4, stream);

    decode_kernel<<<B_*256, 576, 0, stream>>>(scores, deltas, anchors, im_info, outprop, keys, hist16);
    select16_kernel<<<B_, 1024, 0, stream>>>(hist16, state);
    refine_kernel<<<B_, 1024, 0, stream>>>(keys, state);
    collect_kernel<<<B_*16, 1024, 0, stream>>>(keys, state, cand);
    sort_kernel<<<B_, 1024, 0, stream>>>(cand, state, outprop, selbox, livew);
    iou_kernel<<<B_*250, 256, 0, stream>>>(selbox, thrp, supp);
    scan_kernel<<<B_, 1024, 0, stream>>>(supp, livew, selbox, out0);
}

// Round 5
// 391.819 us; speedup vs baseline: 1.5530x; 1.5530x over previous
//
#include <hip/hip_runtime.h>
#include <stdint.h>

#define B_ 16
#define A_ 9
#define H_ 128
#define W_ 128
#define HW_ (H_*W_)
#define N_ (HW_*A_)          // 147456 proposals per image
#define PRE_ 2000
#define POST_ 300
#define CAND_CAP 4096
#define CACHE_ROWS 576       // supp rows prefetched into LDS in scan (~151KB block LDS)

typedef unsigned int u32;
typedef unsigned long long u64;

// ---- workspace layout (bytes) ----
// [state | hist0 | hist1] zeroed by ONE memsetAsync per launch.
#define OFF_STATE  0ull                               // B*8 u32 (pad to 1024)
#define OFF_HIST0  1024ull                            // B*256 u32 = 16384
#define OFF_HIST1  (OFF_HIST0 + 16384ull)             // B*256 u32 = 16384
#define OFF_KEYS   (OFF_HIST1 + 16384ull)
#define OFF_CAND   (OFF_KEYS + (u64)B_*N_*4)
#define OFF_SELBOX (OFF_CAND + (u64)B_*CAND_CAP*8)
#define OFF_LIVE   (OFF_SELBOX + (u64)B_*PRE_*16)
#define OFF_SUPP   (OFF_LIVE + (u64)B_*32*8)
// end = OFF_SUPP + B*PRE*32*8  (~18.7 MB total)

__device__ __forceinline__ u32 mono_key(float f) {
    u32 u = __float_as_uint(f);
    return (u & 0x80000000u) ? ~u : (u | 0x80000000u);
}

__device__ __forceinline__ u64 shfl64(u64 v, int src) {
    u32 lo = (u32)__shfl((int)(u32)(v & 0xFFFFFFFFull), src);
    u32 hi = (u32)__shfl((int)(u32)(v >> 32), src);
    return ((u64)hi << 32) | lo;
}

// wave-level select over a 256-bin histogram: find bin s.t. suffix-count crosses `need`.
// Must be called by a full wave; the matching lane writes {bin, need-above} to out[0..1].
__device__ __forceinline__ void wave_select256(const u32* __restrict__ hh, u32 need,
                                               u32* __restrict__ out) {
    int lane = threadIdx.x & 63;
    uint4 hv = ((const uint4*)hh)[lane];               // bins 4l..4l+3
    u32 psum = hv.x + hv.y + hv.z + hv.w;
    u32 s = psum;                                      // wave-inclusive suffix sum
    #pragma unroll
    for (int off = 1; off < 64; off <<= 1) {
        u32 o = (u32)__shfl_down((int)s, off);
        if (lane + off < 64) s += o;
    }
    u32 S_next = (u32)__shfl_down((int)s, 1);
    if (lane == 63) S_next = 0;
    u32 above[4], cnt[4];
    above[3] = S_next;             cnt[3] = hv.w;
    above[2] = S_next + hv.w;      cnt[2] = hv.z;
    above[1] = above[2] + hv.z;    cnt[1] = hv.y;
    above[0] = above[1] + hv.y;    cnt[0] = hv.x;
    #pragma unroll
    for (int j = 3; j >= 0; --j) {
        if (above[j] < need && above[j] + cnt[j] >= need) {
            out[0] = (u32)(4*lane + j);
            out[1] = need - above[j];
        }
    }
}

// ---------------- stage 1: decode + fg scores + keys + LDS-aggregated 8-bit hist ----------------
// block = 576 threads (wave a=0..8, lane = p offset); coalesced reads AND writes.
__global__ __launch_bounds__(576) void decode_kernel(
        const float* __restrict__ scores,
        const float* __restrict__ deltas,
        const float* __restrict__ anchors,
        const float* __restrict__ im_info,
        float* __restrict__ outprop,
        u32* __restrict__ keys,
        u32* __restrict__ hist0) {
    __shared__ float4 tile[9][65];   // +1 pad
    __shared__ float4 sbase[A_];
    __shared__ u32 h[256];
    int tid = threadIdx.x;
    int a = tid >> 6, lane = tid & 63;
    if (tid < A_) sbase[tid] = ((const float4*)anchors)[tid];  // anchors[p=0] == base anchors
    if (tid < 256) h[tid] = 0;
    __syncthreads();

    int b  = blockIdx.x >> 8;
    int pb = blockIdx.x & 255;
    int p0 = pb << 6;
    int p  = p0 + lane;

    float s0 = scores[((b*2*A_ + a)      << 14) + p];
    float s1 = scores[((b*2*A_ + A_ + a) << 14) + p];
    float m  = fmaxf(s0, s1);
    float e0 = expf(s0 - m);
    float e1 = expf(s1 - m);
    float fg = e1 / (e0 + e1);

    float4 base = sbase[a];
    int ix = p & (W_-1), iy = p >> 7;
    float sx = (float)(ix * 16), sy = (float)(iy * 16);
    float ax1 = base.x + sx, ay1 = base.y + sy, ax2 = base.z + sx, ay2 = base.w + sy;

    float w  = ax2 - ax1 + 1.0f;
    float h_ = ay2 - ay1 + 1.0f;
    float cx = ax1 + 0.5f*w;
    float cy = ay1 + 0.5f*h_;

    const float* dbase = deltas + (u64)(((b*4*A_ + 4*a) << 14) + p);
    float dx = dbase[0];
    float dy = dbase[HW_];
    float dw = dbase[2*HW_];
    float dh = dbase[3*HW_];

    float pcx = dx*w  + cx;
    float pcy = dy*h_ + cy;
    float pw  = expf(dw)*w;
    float ph  = expf(dh)*h_;
    float x1 = pcx - 0.5f*pw, y1 = pcy - 0.5f*ph;
    float x2 = pcx + 0.5f*pw, y2 = pcy + 0.5f*ph;

    float wmax = im_info[b*4 + 1] - 1.0f;
    float hmax = im_info[b*4 + 0] - 1.0f;
    x1 = fminf(fmaxf(x1, 0.0f), wmax);
    y1 = fminf(fmaxf(y1, 0.0f), hmax);
    x2 = fminf(fmaxf(x2, 0.0f), wmax);
    y2 = fminf(fmaxf(y2, 0.0f), hmax);

    tile[a][lane] = make_float4(x1, y1, x2, y2);

    float bw = x2 - x1 + 1.0f;
    float bh = y2 - y1 + 1.0f;
    bool valid = (bw >= 16.0f*im_info[b*4 + 3]) && (bh >= 16.0f*im_info[b*4 + 2]);
    float sc = valid ? fg : -__builtin_inff();
    u32 k = mono_key(sc);
    keys[((u64)(b*A_ + a) << 14) + p] = k;             // coalesced (a,p) layout
    atomicAdd(&h[k >> 24], 1u);                        // LDS-aggregated 8-bit hist
    __syncthreads();

    // coalesced write-back: n = p*9 + a; block covers n in [p0*9, p0*9 + 576)
    int a2 = tid % 9, pl = tid / 9;
    ((float4*)outprop)[(u64)b*N_ + p0*9 + tid] = tile[a2][pl];

    if (tid < 256 && h[tid]) atomicAdd(&hist0[b*256 + tid], h[tid]);
}

// ---------------- stage 2: 16-bit refine histogram (redundant in-block select8) ----------------
__global__ __launch_bounds__(1024) void hist16_kernel(
        const u32* __restrict__ keys, const u32* __restrict__ hist0,
        u32* __restrict__ hist1) {
    int b = blockIdx.x >> 4;
    int slice = blockIdx.x & 15;
    int tid = threadIdx.x;
    __shared__ u32 sel[2];      // {bin8, rem8}
    __shared__ u32 h[256];
    if (tid < 64) wave_select256(hist0 + b*256, (u32)PRE_, sel);
    for (int i = tid; i < 256; i += 1024) h[i] = 0;
    __syncthreads();
    u32 pfx = sel[0];
    const u32* kb = keys + (u64)b*N_ + slice*(N_/16);
    for (int n = tid; n < N_/16; n += 1024) {
        u32 k = kb[n];
        if ((k >> 24) == pfx) atomicAdd(&h[(k >> 16) & 255u], 1u);
    }
    __syncthreads();
    for (int i = tid; i < 256; i += 1024)
        if (h[i]) atomicAdd(&hist1[b*256 + i], h[i]);
}

// ---------------- stage 3: collect all keys >= T (redundant select8 + select16) ----------------
__global__ __launch_bounds__(1024) void collect_kernel(
        const u32* __restrict__ keys, const u32* __restrict__ hist0,
        const u32* __restrict__ hist1, u32* __restrict__ state,
        u64* __restrict__ cand) {
    int b = blockIdx.x >> 4;
    int slice = blockIdx.x & 15;
    int tid = threadIdx.x;
    __shared__ u32 sel8[2], sel16[2];
    if (tid < 64) wave_select256(hist0 + b*256, (u32)PRE_, sel8);
    __syncthreads();
    if (tid < 64) wave_select256(hist1 + b*256, sel8[1], sel16);
    __syncthreads();
    u32 T = (sel8[0] << 24) | (sel16[0] << 16);        // threshold key
    const u32* kb = keys + (u64)b*N_ + slice*(N_/16);
    u64* cb = cand + (u64)b*CAND_CAP;
    for (int i = tid; i < N_/16; i += 1024) {
        u32 k = kb[i];
        if (k >= T) {
            u32 pos = atomicAdd(&state[b*8 + 2], 1u);
            int idx = slice*(N_/16) + i;
            u32 n = (u32)((idx & (HW_-1))*A_ + (idx >> 14));  // n = p*9 + a
            if (pos < CAND_CAP) cb[pos] = ((u64)k << 32) | (u32)(~n);  // key desc, index asc
        }
    }
}

// ---------------- stage 4: bitonic sort candidates, gather top-2000 boxes ----------------
__global__ __launch_bounds__(1024) void sort_kernel(
        const u64* __restrict__ cand, const u32* __restrict__ state,
        const float* __restrict__ outprop,
        float4* __restrict__ selbox, u64* __restrict__ livew) {
    int b = blockIdx.x, tid = threadIdx.x;
    __shared__ u64 s[CAND_CAP];
    __shared__ unsigned char lv[2048];
    u32 cnt = state[b*8 + 2];
    if (cnt > CAND_CAP) cnt = CAND_CAP;
    const u64* cb = cand + (u64)b*CAND_CAP;
    for (int i = tid; i < CAND_CAP; i += 1024) s[i] = (i < (int)cnt) ? cb[i] : 0ull;
    for (int i = tid; i < 2048; i += 1024) lv[i] = 0;

    for (u32 k = 2; k <= CAND_CAP; k <<= 1) {
        for (u32 j = k >> 1; j > 0; j >>= 1) {
            __syncthreads();
            for (u32 e = tid; e < CAND_CAP; e += 1024) {
                u32 ixj = e ^ j;
                if (ixj > e) {
                    u64 x = s[e], y = s[ixj];
                    bool descend = ((e & k) == 0);
                    if (descend ? (x < y) : (x > y)) { s[e] = y; s[ixj] = x; }
                }
            }
        }
    }
    __syncthreads();
    for (int r = tid; r < PRE_; r += 1024) {
        u64 e = s[r];
        u32 key = (u32)(e >> 32);
        u32 n = ~(u32)e;
        float4 box = make_float4(0.f, 0.f, 0.f, 0.f);
        if (e != 0ull) box = ((const float4*)outprop)[(u64)b*N_ + n];
        selbox[(u64)b*PRE_ + r] = box;
        lv[r] = (key >= 0x80000000u) ? 1 : 0;   // finite (valid) score
    }
    __syncthreads();
    for (int w = tid; w < 32; w += 1024) {
        u64 word = 0;
        for (int bit = 0; bit < 64; ++bit) {
            int r = w*64 + bit;
            if (r < PRE_ && lv[r]) word |= (1ull << bit);
        }
        livew[b*32 + w] = word;
    }
}

// ---------------- stage 5: 2000x2000 IoU suppression bitmask (full-device parallel) ----------------
__global__ __launch_bounds__(256) void iou_kernel(
        const float4* __restrict__ selbox, const float* __restrict__ thrp,
        u64* __restrict__ supp) {
    int bi = blockIdx.x;             // B * 250 blocks, 8 rows each
    int b = bi / 250;
    int rbase = (bi % 250) * 8;
    int tid = threadIdx.x;
    __shared__ float4 box[PRE_];
    for (int i = tid; i < PRE_; i += 256) box[i] = selbox[(u64)b*PRE_ + i];
    __syncthreads();
    float thresh = thrp[0];
    int wv = tid >> 6, lane = tid & 63;

    float4 p[8]; float ai[8];
    #pragma unroll
    for (int r = 0; r < 8; ++r) {
        p[r]  = box[rbase + r];
        ai[r] = (p[r].z - p[r].x + 1.f) * (p[r].w - p[r].y + 1.f);
    }
    for (int c = 0; c < 8; ++c) {
        int j = c*256 + tid;
        bool inb = (j < PRE_);
        float4 q = box[inb ? j : 0];
        float aj = (q.z - q.x + 1.f) * (q.w - q.y + 1.f);
        #pragma unroll
        for (int r = 0; r < 8; ++r) {
            float iw = fminf(p[r].z, q.z) - fmaxf(p[r].x, q.x) + 1.f;
            float ih = fminf(p[r].w, q.w) - fmaxf(p[r].y, q.y) + 1.f;
            iw = fmaxf(iw, 0.f); ih = fmaxf(ih, 0.f);
            float inter = iw * ih;
            bool pred = inb && ((inter / (ai[r] + aj - inter)) > thresh);
            u64 ball = __ballot(pred);
            if (lane == 0)
                supp[((u64)(b*PRE_ + rbase + r))*32 + (c*4 + wv)] = ball;
        }
    }
}

// ---------------- stage 6: greedy scan (register state, shfl-only chain) + output ----------------
__global__ __launch_bounds__(1024) void scan_kernel(
        const u64* __restrict__ supp, const u64* __restrict__ livew,
        const float4* __restrict__ selbox, float* __restrict__ out0) {
    int b = blockIdx.x;
    int tid = threadIdx.x;
    int wave = tid >> 6, lane = tid & 63;

    __shared__ u64 rows[CACHE_ROWS][32];     // 147456 B
    __shared__ int rowof[CACHE_ROWS];
    __shared__ int kept[POST_];
    __shared__ int s_kc, s_nlive;

    // wave 0: live words, per-lane exclusive prefix, rowof enumeration
    u64 ow = 0; int pr = 0;
    if (wave == 0) {
        u64 w = (lane < 32) ? livew[b*32 + lane] : 0ull;
        ow = w;
        int pc = (int)__builtin_popcountll(w);
        int x = pc;
        #pragma unroll
        for (int off = 1; off < 64; off <<= 1) {
            int y = __shfl_up(x, off);
            if (lane >= off) x += y;
        }
        pr = x - pc;
        if (lane == 31) s_nlive = x;
        int c = 0;
        u64 t = w;
        while (t) {
            int bit = (int)__builtin_ctzll(t);
            t &= t - 1;
            int slot = pr + c; c++;
            if (slot < CACHE_ROWS) rowof[slot] = lane*64 + bit;
        }
    }
    if (tid == 0) s_kc = 0;
    __syncthreads();

    int nslot = s_nlive < CACHE_ROWS ? s_nlive : CACHE_ROWS;
    for (int s = wave; s < nslot; s += 16) {
        int r = rowof[s];
        if (lane < 32) rows[s][lane] = supp[((u64)(b*PRE_ + r))*32 + lane];
    }
    __syncthreads();

    if (wave == 0) {
        u64 alive = ow;
        u64 gt = ~0ull;
        int kc = 0;
        while (kc < POST_) {
            u64 m = alive & gt;
            u64 bal = __ballot(m != 0ull);
            if (!bal) break;
            int w2 = (int)__builtin_ctzll(bal);
            u64 word = shfl64(m, w2);
            int nxt = (w2 << 6) | (int)__builtin_ctzll(word);
            if (lane == 0) kept[kc] = nxt;
            kc++;
            int nbit = nxt & 63;
            u64 below = (nbit == 0) ? 0ull : (~0ull >> (64 - nbit));
            u64 ow2 = shfl64(ow, w2);
            int pr2 = __shfl(pr, w2);
            int rk = pr2 + (int)__builtin_popcountll(ow2 & below);
            u64 gt2;
            if (lane > w2)       gt2 = ~0ull;
            else if (lane == w2) gt2 = (nbit == 63) ? 0ull : (~0ull << (nbit + 1));
            else                 gt2 = 0ull;
            u64 rv = 0ull;
            if (lane < 32)
                rv = (rk < nslot) ? rows[rk][lane]
                                  : supp[((u64)(b*PRE_ + nxt))*32 + lane];
            alive &= ~(rv & gt2);
            gt = gt2;
        }
        if (lane == 0) s_kc = kc;
    }
    __syncthreads();

    int kc = s_kc;
    for (int r = tid; r < POST_; r += 1024) {
        int i = (r < kc) ? kept[r] : -1;
        float o1 = 0.f, o2 = 0.f, o3 = 0.f, o4 = 0.f;
        if (i >= 0) {
            float4 bx = selbox[(u64)b*PRE_ + i];
            o1 = bx.x; o2 = bx.y; o3 = bx.z; o4 = bx.w;
        }
        float* rowp = out0 + (u64)(b*POST_ + r)*5;
        rowp[0] = (float)b;
        rowp[1] = o1; rowp[2] = o2; rowp[3] = o3; rowp[4] = o4;
    }
}

extern "C" void kernel_launch(void* const* d_in, const int* in_sizes, int n_in,
                              void* d_out, int out_size, void* d_ws, size_t ws_size,
                              hipStream_t stream) {
    const float* scores  = (const float*)d_in[0];
    const float* deltas  = (const float*)d_in[1];
    const float* anchors = (const float*)d_in[2];
    const float* im_info = (const float*)d_in[3];
    const float* thrp    = (const float*)d_in[7];   // nms_thresh

    float* out0    = (float*)d_out;                 // (16, 300, 5)
    float* outprop = out0 + (u64)B_*POST_*5;        // (16, 147456, 4)

    char* ws = (char*)d_ws;
    u32*    state  = (u32*)   (ws + OFF_STATE);
    u32*    hist0  = (u32*)   (ws + OFF_HIST0);
    u32*    hist1  = (u32*)   (ws + OFF_HIST1);
    u32*    keys   = (u32*)   (ws + OFF_KEYS);
    u64*    cand   = (u64*)   (ws + OFF_CAND);
    float4* selbox = (float4*)(ws + OFF_SELBOX);
    u64*    livew  = (u64*)   (ws + OFF_LIVE);
    u64*    supp   = (u64*)   (ws + OFF_SUPP);

    hipMemsetAsync(ws, 0, OFF_KEYS, stream);        // state + hist0 + hist1

    decode_kernel<<<B_*256, 576, 0, stream>>>(scores, deltas, anchors, im_info, outprop, keys, hist0);
    hist16_kernel<<<B_*16, 1024, 0, stream>>>(keys, hist0, hist1);
    collect_kernel<<<B_*16, 1024, 0, stream>>>(keys, hist0, hist1, state, cand);
    sort_kernel<<<B_, 1024, 0, stream>>>(cand, state, outprop, selbox, livew);
    iou_kernel<<<B_*250, 256, 0, stream>>>(selbox, thrp, supp);
    scan_kernel<<<B_, 1024, 0, stream>>>(supp, livew, selbox, out0);
}